// Round 8
// baseline (121.074 us; speedup 1.0000x reference)
//
#include <hip/hip_runtime.h>
#include <math.h>

#define N_NODES 10000
#define N_EDGES 160000
#define D 512

// =============================================================== K1
// blocks [0,256): V_b[k,c] = sum_n W2_b[k][n]*F_b[n][c]   (wave per (b,k))
// blocks [256,296): zero cnt0/cnt1/p0/p1/zacc

__global__ __launch_bounds__(256) void k1_vproj_zero(
    const float* __restrict__ W2i, const float* __restrict__ W2o,
    const float* __restrict__ fcw, float2* __restrict__ V,
    int* __restrict__ cnt0, int* __restrict__ cnt1,
    float2* __restrict__ p0, float2* __restrict__ p1, float2* __restrict__ zacc) {
    int bid = blockIdx.x;
    if (bid < 256) {
        int wv = bid * 4 + (threadIdx.x >> 6);
        int lane = threadIdx.x & 63;
        int b = wv >> 9, k = wv & 511;
        const float* W = b ? W2o : W2i;
        const float* F = fcw + b * 1024;
        float v0 = 0.f, v1 = 0.f;
        for (int n = lane; n < 512; n += 64) {
            float w = W[k * 512 + n];
            v0 += w * F[2 * n];
            v1 += w * F[2 * n + 1];
        }
#pragma unroll
        for (int off = 32; off; off >>= 1) {
            v0 += __shfl_down(v0, off);
            v1 += __shfl_down(v1, off);
        }
        if (lane == 0) V[wv] = make_float2(v0, v1);
    } else {
        int tid = (bid - 256) * 256 + threadIdx.x;
        if (tid < N_NODES) {
            cnt0[tid] = 0;
            cnt1[tid] = 0;
            p0[tid] = make_float2(0.f, 0.f);
            p1[tid] = make_float2(0.f, 0.f);
            zacc[tid] = make_float2(0.f, 0.f);
        }
    }
}

// =============================================================== K2
// blocks [0,1250): degree count (int atomics, both branches)
// blocks [1250,1507): U_b[j,c] = sum_k W1_b[j][k]*V_b[k,c]; tail wave: beta1, cvec

__global__ __launch_bounds__(256) void k2_deg_uproj(
    const int* __restrict__ ein, const int* __restrict__ eout,
    int* __restrict__ cnt0, int* __restrict__ cnt1,
    const float* __restrict__ W1i, const float* __restrict__ W1o,
    const float2* __restrict__ V,
    const float* __restrict__ b1i, const float* __restrict__ b1o,
    const float* __restrict__ b2i, const float* __restrict__ b2o,
    const float* __restrict__ fcw, const float* __restrict__ fcb,
    float2* __restrict__ U, float2* __restrict__ beta1, float2* __restrict__ cvec) {
    int bid = blockIdx.x;
    if (bid < 1250) {
        int i = bid * 256 + threadIdx.x;
        if (i < N_EDGES) atomicAdd(&cnt0[ein[N_EDGES + i]], 1);
        else if (i < 2 * N_EDGES) atomicAdd(&cnt1[eout[i]], 1);  // i-E+E = i
        return;
    }
    int wv = (bid - 1250) * 4 + (threadIdx.x >> 6);
    int lane = threadIdx.x & 63;
    if (wv < 1024) {
        int b = wv >> 9, j = wv & 511;
        const float* W = b ? W1o : W1i;
        const float2* Vb = V + b * 512;
        float u0 = 0.f, u1 = 0.f;
        for (int k = lane; k < 512; k += 64) {
            float w = W[j * 512 + k];
            float2 v = Vb[k];
            u0 += w * v.x;
            u1 += w * v.y;
        }
#pragma unroll
        for (int off = 32; off; off >>= 1) {
            u0 += __shfl_down(u0, off);
            u1 += __shfl_down(u1, off);
        }
        if (lane == 0) U[wv] = make_float2(u0, u1);
    } else if (wv == 1024) {
        float a00 = 0.f, a01 = 0.f, a10 = 0.f, a11 = 0.f, c0 = 0.f, c1 = 0.f;
        for (int k = lane; k < 512; k += 64) {
            float2 v0 = V[k], v1 = V[512 + k];
            a00 += b1i[k] * v0.x;
            a01 += b1i[k] * v0.y;
            a10 += b1o[k] * v1.x;
            a11 += b1o[k] * v1.y;
            c0 += b2i[k] * fcw[2 * k] + b2o[k] * fcw[2 * (512 + k)];
            c1 += b2i[k] * fcw[2 * k + 1] + b2o[k] * fcw[2 * (512 + k) + 1];
        }
#pragma unroll
        for (int off = 32; off; off >>= 1) {
            a00 += __shfl_down(a00, off);
            a01 += __shfl_down(a01, off);
            a10 += __shfl_down(a10, off);
            a11 += __shfl_down(a11, off);
            c0 += __shfl_down(c0, off);
            c1 += __shfl_down(c1, off);
        }
        if (lane == 0) {
            beta1[0] = make_float2(a00, a01);
            beta1[1] = make_float2(a10, a11);
            *cvec = make_float2(c0 + fcb[0], c1 + fcb[1]);
        }
    }
}

// =============================================================== K3
// r_b[i] = TE_b[i,:] @ U_b  (wave per node, lane covers 8 features)
// + dinv_b[i] = rsqrt(deg+1)

__global__ __launch_bounds__(256) void k3_r(
    const float* __restrict__ x, const float* __restrict__ t,
    const float* __restrict__ w0, const float* __restrict__ b0,
    const float* __restrict__ w1, const float* __restrict__ b1,
    const float2* __restrict__ U,
    const int* __restrict__ cnt0, const int* __restrict__ cnt1,
    float2* __restrict__ r0, float2* __restrict__ r1,
    float* __restrict__ dv0, float* __restrict__ dv1) {
    int node = blockIdx.x * 4 + (threadIdx.x >> 6);
    if (node >= N_NODES) return;
    int lane = threadIdx.x & 63;
    int j0 = lane * 8;
    float tv = t[node];
    float4 xa = *(const float4*)&x[(size_t)node * D + j0];
    float4 xb = *(const float4*)&x[(size_t)node * D + j0 + 4];
    float xv[8] = {xa.x, xa.y, xa.z, xa.w, xb.x, xb.y, xb.z, xb.w};
    float s00 = 0.f, s01 = 0.f, s10 = 0.f, s11 = 0.f;
#pragma unroll
    for (int j = 0; j < 8; ++j) {
        float xx = xv[j];
        float te0 = xx + __cosf(tv * w0[j0 + j] + b0[j0 + j]);
        float te1 = xx + __cosf(tv * w1[j0 + j] + b1[j0 + j]);
        float2 u0 = U[j0 + j];
        float2 u1 = U[512 + j0 + j];
        s00 += te0 * u0.x;
        s01 += te0 * u0.y;
        s10 += te1 * u1.x;
        s11 += te1 * u1.y;
    }
#pragma unroll
    for (int off = 32; off; off >>= 1) {
        s00 += __shfl_down(s00, off);
        s01 += __shfl_down(s01, off);
        s10 += __shfl_down(s10, off);
        s11 += __shfl_down(s11, off);
    }
    if (lane == 0) {
        r0[node] = make_float2(s00, s01);
        r1[node] = make_float2(s10, s11);
        dv0[node] = rsqrtf((float)cnt0[node] + 1.0f);
        dv1[node] = rsqrtf((float)cnt1[node] + 1.0f);
    }
}

// =============================================================== K4
// edge-parallel scatter: pacc_b[d] += dinv[s]*dinv[d] * r_b[s]

__global__ __launch_bounds__(256) void k4_scatter_p(
    const int* __restrict__ ein, const int* __restrict__ eout,
    const float* __restrict__ dv0, const float* __restrict__ dv1,
    const float2* __restrict__ r0, const float2* __restrict__ r1,
    float2* __restrict__ p0, float2* __restrict__ p1) {
    int i = blockIdx.x * 256 + threadIdx.x;
    if (i >= 2 * N_EDGES) return;
    int br = i >= N_EDGES;
    int e = i - br * N_EDGES;
    const int* ei = br ? eout : ein;
    const float* dv = br ? dv1 : dv0;
    const float2* rr = br ? r1 : r0;
    float* pp = (float*)(br ? p1 : p0);
    int s = ei[e], d = ei[N_EDGES + e];
    float c = dv[s] * dv[d];
    float2 rv = rr[s];
    atomicAdd(&pp[2 * d], c * rv.x);
    atomicAdd(&pp[2 * d + 1], c * rv.y);
}

// =============================================================== K5
// edge-parallel scatter: zacc[d] += dinv[s]*dinv[d] * p_full_b[s]
// p_full_b[s] = pacc_b[s] + beta1_b + dinv[s]^2 * r_b[s]   (computed on the fly)

__global__ __launch_bounds__(256) void k5_scatter_z(
    const int* __restrict__ ein, const int* __restrict__ eout,
    const float* __restrict__ dv0, const float* __restrict__ dv1,
    const float2* __restrict__ r0, const float2* __restrict__ r1,
    const float2* __restrict__ p0, const float2* __restrict__ p1,
    const float2* __restrict__ beta1, float2* __restrict__ zacc) {
    int i = blockIdx.x * 256 + threadIdx.x;
    if (i >= 2 * N_EDGES) return;
    int br = i >= N_EDGES;
    int e = i - br * N_EDGES;
    const int* ei = br ? eout : ein;
    const float* dv = br ? dv1 : dv0;
    const float2* rr = br ? r1 : r0;
    const float2* pp = br ? p1 : p0;
    int s = ei[e], d = ei[N_EDGES + e];
    float ds = dv[s];
    float c = ds * dv[d];
    float2 pv = pp[s];
    float2 rv = rr[s];
    float2 bb = beta1[br];
    float fx = pv.x + bb.x + ds * ds * rv.x;
    float fy = pv.y + bb.y + ds * ds * rv.y;
    float* zp = (float*)zacc;
    atomicAdd(&zp[2 * d], c * fx);
    atomicAdd(&zp[2 * d + 1], c * fy);
}

// =============================================================== K6
// z_full[i] = zacc[i] + sum_b dinv_b[i]^2 * p_full_b[i] + cvec ; log_softmax

__global__ __launch_bounds__(256) void k6_lsm(
    const float2* __restrict__ zacc,
    const float2* __restrict__ p0, const float2* __restrict__ p1,
    const float2* __restrict__ r0, const float2* __restrict__ r1,
    const float* __restrict__ dv0, const float* __restrict__ dv1,
    const float2* __restrict__ beta1, const float2* __restrict__ cvec,
    float* __restrict__ out) {
    int i = blockIdx.x * 256 + threadIdx.x;
    if (i >= N_NODES) return;
    float2 z = zacc[i];
    float2 cv = *cvec;
    float2 b0 = beta1[0], b1 = beta1[1];
    float d0 = dv0[i], d1 = dv1[i];
    float2 pa = p0[i], ra = r0[i];
    float2 pb = p1[i], rb = r1[i];
    float s0 = d0 * d0, s1 = d1 * d1;
    float pf0x = pa.x + b0.x + s0 * ra.x, pf0y = pa.y + b0.y + s0 * ra.y;
    float pf1x = pb.x + b1.x + s1 * rb.x, pf1y = pb.y + b1.y + s1 * rb.y;
    float z0 = z.x + s0 * pf0x + s1 * pf1x + cv.x;
    float z1 = z.y + s0 * pf0y + s1 * pf1y + cv.y;
    float m = fmaxf(z0, z1);
    float l2 = m + logf(expf(z0 - m) + expf(z1 - m));
    out[i * 2 + 0] = z0 - l2;
    out[i * 2 + 1] = z1 - l2;
}

// ---------------------------------------------------------------- launch

extern "C" void kernel_launch(void* const* d_in, const int* in_sizes, int n_in,
                              void* d_out, int out_size, void* d_ws, size_t ws_size,
                              hipStream_t stream) {
    const float* x        = (const float*)d_in[0];
    const int*   ein      = (const int*)d_in[1];
    const int*   eout     = (const int*)d_in[2];
    const float* t        = (const float*)d_in[3];
    const float* te_w[2]  = {(const float*)d_in[4], (const float*)d_in[10]};
    const float* te_b[2]  = {(const float*)d_in[5], (const float*)d_in[11]};
    const float* W1[2]    = {(const float*)d_in[6], (const float*)d_in[12]};
    const float* b1[2]    = {(const float*)d_in[7], (const float*)d_in[13]};
    const float* W2[2]    = {(const float*)d_in[8], (const float*)d_in[14]};
    const float* b2[2]    = {(const float*)d_in[9], (const float*)d_in[15]};
    const float* fc_w     = (const float*)d_in[16];
    const float* fc_b     = (const float*)d_in[17];
    float* out = (float*)d_out;

    char* p = (char*)d_ws;
    auto carve = [&](size_t bytes) {
        void* r = (void*)p;
        p += ((bytes + 255) / 256) * 256;
        return r;
    };
    float2* V     = (float2*)carve((size_t)1024 * 8);
    float2* U     = (float2*)carve((size_t)1024 * 8);
    float2* beta1 = (float2*)carve(2 * 8);
    float2* cvec  = (float2*)carve(8);
    float2* rbuf[2];
    rbuf[0] = (float2*)carve((size_t)N_NODES * 8);
    rbuf[1] = (float2*)carve((size_t)N_NODES * 8);
    float2* pbuf[2];
    pbuf[0] = (float2*)carve((size_t)N_NODES * 8);
    pbuf[1] = (float2*)carve((size_t)N_NODES * 8);
    float2* zacc = (float2*)carve((size_t)N_NODES * 8);
    int*   cnt[2];  cnt[0]  = (int*)carve(N_NODES * 4);   cnt[1]  = (int*)carve(N_NODES * 4);
    float* dinv[2]; dinv[0] = (float*)carve(N_NODES * 4); dinv[1] = (float*)carve(N_NODES * 4);

    // K1: vproj (256 blocks) + zero-init (40 blocks)
    k1_vproj_zero<<<296, 256, 0, stream>>>(W2[0], W2[1], fc_w, V,
                                           cnt[0], cnt[1], pbuf[0], pbuf[1], zacc);
    // K2: degree atomics (1250 blocks) + uproj (257 blocks)
    k2_deg_uproj<<<1507, 256, 0, stream>>>(ein, eout, cnt[0], cnt[1],
                                           W1[0], W1[1], V, b1[0], b1[1],
                                           b2[0], b2[1], fc_w, fc_b, U, beta1, cvec);
    // K3: r + dinv
    k3_r<<<(N_NODES + 3) / 4, 256, 0, stream>>>(
        x, t, te_w[0], te_b[0], te_w[1], te_b[1], U,
        cnt[0], cnt[1], rbuf[0], rbuf[1], dinv[0], dinv[1]);
    // K4: scatter p
    k4_scatter_p<<<(2 * N_EDGES + 255) / 256, 256, 0, stream>>>(
        ein, eout, dinv[0], dinv[1], rbuf[0], rbuf[1], pbuf[0], pbuf[1]);
    // K5: scatter z
    k5_scatter_z<<<(2 * N_EDGES + 255) / 256, 256, 0, stream>>>(
        ein, eout, dinv[0], dinv[1], rbuf[0], rbuf[1], pbuf[0], pbuf[1], beta1, zacc);
    // K6: self terms + log_softmax
    k6_lsm<<<(N_NODES + 255) / 256, 256, 0, stream>>>(
        zacc, pbuf[0], pbuf[1], rbuf[0], rbuf[1], dinv[0], dinv[1], beta1, cvec, out);
}